// Round 1
// baseline (517.988 us; speedup 1.0000x reference)
//
#include <hip/hip_runtime.h>

// out[a,bc,d,g] = (1/3) * sum_{e,f} T1[a,bc,d,e,f] * T2[bc,e,f,g]
// A=4, BC=131072*6=786432, slabs are 27 floats (d,e,f) / (e,f,g), out 9 floats (d,g).
// Memory-bound: ~538 MB total traffic -> ~85us floor at 6.3 TB/s.

#define A_        4
#define BC_       786432
#define TILE_     64          // bc slabs per block
#define NTHREADS  256         // 4 a * 64 bc_local

// float4-unit strides
#define T1_A_STRIDE4   5308416   // BC_*27/4
#define OUT_A_STRIDE4  1769472   // BC_*9/4
#define T1_TILE4       432       // TILE_*27/4 per a-region
#define T2_TILE4       432
#define OUT_TILE4      144       // TILE_*9/4 per a-region

__global__ __launch_bounds__(NTHREADS, 4)
void prod_einsum_kernel(const float* __restrict__ T1,
                        const float* __restrict__ T2,
                        float* __restrict__ Out) {
    // smem layout: [0, 6912) T1 tile (4*64*27 floats), [6912, 8640) T2 tile (64*27)
    // After compute, front of smem is reused as the output staging tile (2304 floats).
    __shared__ float smem[8640];
    float4* smem4 = (float4*)smem;

    const float4* T1v = (const float4*)T1;
    const float4* T2v = (const float4*)T2;
    float4* Outv = (float4*)Out;

    const int tid = threadIdx.x;
    const int blk = blockIdx.x;

    // ---- Stage T1: 4 regions of 432 float4, flattened to 1728 ----
    for (int j = tid; j < 4 * T1_TILE4; j += NTHREADS) {
        int a = j / T1_TILE4;
        int r = j - a * T1_TILE4;
        smem4[j] = T1v[a * T1_A_STRIDE4 + blk * T1_TILE4 + r];
    }
    // ---- Stage T2: 432 float4 ----
    for (int j = tid; j < T2_TILE4; j += NTHREADS) {
        smem4[1728 + j] = T2v[blk * T2_TILE4 + j];
    }
    __syncthreads();

    // ---- Compute: thread = (a, bc_local) ----
    const int a = tid >> 6;
    const int l = tid & 63;
    const float* t1 = smem + (a * TILE_ + l) * 27;
    const float* t2 = smem + 6912 + l * 27;

    float r1[27], r2[27];
    #pragma unroll
    for (int i = 0; i < 27; ++i) r1[i] = t1[i];
    #pragma unroll
    for (int i = 0; i < 27; ++i) r2[i] = t2[i];

    float acc[9];
    #pragma unroll
    for (int d = 0; d < 3; ++d) {
        #pragma unroll
        for (int g = 0; g < 3; ++g) {
            float s = 0.0f;
            #pragma unroll
            for (int e = 0; e < 3; ++e) {
                #pragma unroll
                for (int f = 0; f < 3; ++f) {
                    s += r1[d * 9 + e * 3 + f] * r2[e * 9 + f * 3 + g];
                }
            }
            acc[d * 3 + g] = s * (1.0f / 3.0f);
        }
    }

    __syncthreads();  // all LDS reads done; safe to overwrite front of smem

    // ---- Stage output: (a, l, 9) packed = 2304 floats ----
    #pragma unroll
    for (int i = 0; i < 9; ++i) {
        smem[(a * TILE_ + l) * 9 + i] = acc[i];
    }
    __syncthreads();

    // ---- Coalesced write: 4 regions of 144 float4, flattened to 576 ----
    for (int j = tid; j < 4 * OUT_TILE4; j += NTHREADS) {
        int a2 = j / OUT_TILE4;
        int r = j - a2 * OUT_TILE4;
        Outv[a2 * OUT_A_STRIDE4 + blk * OUT_TILE4 + r] = smem4[j];
    }
}

extern "C" void kernel_launch(void* const* d_in, const int* in_sizes, int n_in,
                              void* d_out, int out_size, void* d_ws, size_t ws_size,
                              hipStream_t stream) {
    const float* T1 = (const float*)d_in[0];
    const float* T2 = (const float*)d_in[1];
    float* Out = (float*)d_out;
    // BC_/TILE_ = 12288 blocks
    prod_einsum_kernel<<<BC_ / TILE_, NTHREADS, 0, stream>>>(T1, T2, Out);
}